// Round 5
// baseline (410.560 us; speedup 1.0000x reference)
//
#include <hip/hip_runtime.h>
#include <stdint.h>
#include <math.h>

typedef __attribute__((ext_vector_type(8))) short short8;   // 8 bf16 (4 VGPRs)
typedef __attribute__((ext_vector_type(4))) float f32x4;    // 4 fp32 acc

typedef __attribute__((address_space(1))) const uint32_t g_u32;
typedef __attribute__((address_space(3))) uint32_t l_u32;

static __device__ __forceinline__ uint16_t f2bf(float f) {
  union { float f; uint32_t u; } v; v.f = f;
  uint32_t r = (v.u + 0x7FFFu + ((v.u >> 16) & 1u)) >> 16;  // RNE
  return (uint16_t)r;
}

static __device__ __forceinline__ float bf2f(uint16_t u) {
  union { uint32_t u; float f; } v; v.u = ((uint32_t)u) << 16;
  return v.f;
}

static __device__ __forceinline__ uint32_t cvt_pk_bf16(float lo, float hi) {
  uint32_t r;
  asm("v_cvt_pk_bf16_f32 %0, %1, %2" : "=v"(r) : "v"(lo), "v"(hi));  // RNE pack
  return r;
}

static __device__ __forceinline__ float waveReduceSum(float x) {
#pragma unroll
  for (int m = 32; m > 0; m >>= 1) x += __shfl_xor(x, m, 64);
  return x;
}

// ---------------- zero the atomically-accumulated arrays (replaces memset)
__global__ __launch_bounds__(256) void k_zero(float* __restrict__ p, int n4) {
  const int i = blockIdx.x * 256 + threadIdx.x;
  if (i < n4) reinterpret_cast<float4*>(p)[i] = float4{0.f, 0.f, 0.f, 0.f};
}

// ---------------- N pass: b_i = ||n_i||^2, sn_l = sum_i N[i][l], Nt = bf16 N^T
// pre-swizzled per 32-k tile so a LINEAR 16KB gll copy yields swizzled LDS:
//   tile byte(l, k') = l*64 + ((k'>>3) ^ (l&3))*16 + (k'&7)*2,  k' in [0,32)
__global__ __launch_bounds__(256) void k_nt(const float* __restrict__ N,
                                            uint16_t* __restrict__ Nt,
                                            float* __restrict__ b,
                                            float* __restrict__ sn) {
  __shared__ __align__(16) uint16_t T[256 * 72];  // [l][k] k=0..63, pad 72
  const int i0 = blockIdx.x * 64;
  const int tid = threadIdx.x;
  const int wave = tid >> 6, lane = tid & 63;
  float sq[16];
  float snacc0 = 0.f, snacc1 = 0.f, snacc2 = 0.f, snacc3 = 0.f;
#pragma unroll
  for (int it = 0; it < 16; ++it) {
    const int k = wave + it * 4;
    const int l4 = lane * 4;
    const float4 v = *reinterpret_cast<const float4*>(N + (size_t)(i0 + k) * 256 + l4);
    T[(l4 + 0) * 72 + k] = f2bf(v.x);
    T[(l4 + 1) * 72 + k] = f2bf(v.y);
    T[(l4 + 2) * 72 + k] = f2bf(v.z);
    T[(l4 + 3) * 72 + k] = f2bf(v.w);
    sq[it] = v.x * v.x + v.y * v.y + v.z * v.z + v.w * v.w;
    snacc0 += v.x; snacc1 += v.y; snacc2 += v.z; snacc3 += v.w;
  }
#pragma unroll
  for (int m = 1; m < 64; m <<= 1) {
#pragma unroll
    for (int it = 0; it < 16; ++it) sq[it] += __shfl_xor(sq[it], m, 64);
  }
  float myv = sq[0];
#pragma unroll
  for (int it = 1; it < 16; ++it) myv = (lane == it) ? sq[it] : myv;
  if (lane < 16) b[i0 + wave + lane * 4] = myv;
  {
    const int l4 = lane * 4;
    atomicAdd(&sn[l4 + 0], snacc0); atomicAdd(&sn[l4 + 1], snacc1);
    atomicAdd(&sn[l4 + 2], snacc2); atomicAdd(&sn[l4 + 3], snacc3);
  }
  __syncthreads();
  const int l = tid;
#pragma unroll
  for (int tt = 0; tt < 2; ++tt) {
    const int tg = blockIdx.x * 2 + tt;
#pragma unroll
    for (int c = 0; c < 4; ++c) {
      const short8 v = *reinterpret_cast<const short8*>(&T[l * 72 + tt * 32 + c * 8]);
      *reinterpret_cast<short8*>((char*)Nt + (size_t)tg * 16384 + l * 64 +
                                 ((c ^ (l & 3)) << 4)) = v;
    }
  }
}

// ---------------- h1_i = sum_l N[i][l] * sn[l]
__global__ __launch_bounds__(256) void k_h1(const float* __restrict__ N,
                                            const float* __restrict__ sn,
                                            float* __restrict__ h1) {
  const int wave = threadIdx.x >> 6, lane = threadIdx.x & 63;
  const int i = blockIdx.x * 4 + wave;
  const float4 v = *reinterpret_cast<const float4*>(N + (size_t)i * 256 + lane * 4);
  const float4 s = *reinterpret_cast<const float4*>(sn + lane * 4);
  float d = v.x * s.x + v.y * s.y + v.z * s.z + v.w * s.w;
  d = waveReduceSum(d);
  if (lane == 0) h1[i] = d;
}

// ---------------- K-split-8 GEMM + fused X statistics (the ONLY full X read).
// Per k-chunk kc (512 rows): M_kc[l][p] = sum_i N[i][l] X[i][p]  (bf16 slices).
// LDS exactly 40 KB -> 4 blocks/CU. ONE barrier per K-step (dbuf makes the
// second redundant). Stats fused on the staged fp32 values.
__global__ __launch_bounds__(256, 4) void k_gemm_f5(const float* __restrict__ X,
                                                    const uint16_t* __restrict__ Nt,
                                                    uint16_t* __restrict__ Mb,
                                                    const float* __restrict__ bvec,
                                                    const float* __restrict__ h1v,
                                                    float* __restrict__ sx,
                                                    float* __restrict__ cx,
                                                    float* __restrict__ scalA,
                                                    int B, int D1) {
  __shared__ __align__(16) uint16_t NB[2][8192];   // 2 x 16 KB (256l x 32k swz)
  __shared__ __align__(16) uint16_t AB[2][2048];   // 2 x 4 KB  (64p x 32k swz)
  const int tid = threadIdx.x;
  const int w = tid >> 6, lane = tid & 63;
  const int lr = lane & 15, lh = lane >> 4;
  const int nks = B >> 8;                 // 16 ksteps per chunk
  const int pt = blockIdx.x >> 3, kc = blockIdx.x & 7;
  const int pbase = pt << 6;
  const int ks0 = kc * nks;               // starting global kstep

  f32x4 acc[4][4];
#pragma unroll
  for (int i = 0; i < 4; ++i)
#pragma unroll
    for (int j = 0; j < 4; ++j) acc[i][j] = (f32x4){0.f, 0.f, 0.f, 0.f};

  // A staging: thread owns col p = tid&63, k-octet w within the 32-row step
  const int ap = tid & 63, ak8 = w << 3;
  const int ab_st = ap * 32 + ((w ^ (ap & 3)) << 3);  // swizzled u16 index
  const float* Xbase = X + (size_t)(ks0 * 32 + ak8) * D1 + pbase + ap;
  float xr[8];
  float4 bv0, bv1, hv0, hv1;
  float s1 = 0.f, sb = 0.f, sh = 0.f, sxa = 0.f, cxa = 0.f;

#define GLL_B(S, BUF)                                                              \
  {                                                                                \
    const char* gsrc_ = (const char*)Nt + (size_t)(ks0 + (S)) * 16384 +            \
                        ((size_t)w << 10) + (size_t)lane * 16;                     \
    _Pragma("unroll")                                                              \
    for (int j_ = 0; j_ < 4; ++j_) {                                               \
      __builtin_amdgcn_global_load_lds((g_u32*)(gsrc_ + ((size_t)j_ << 12)),       \
                                       (l_u32*)&NB[BUF][(j_ * 4 + w) << 9],        \
                                       16, 0, 0);                                  \
    }                                                                              \
  }
#define A_LOADS(S)                                                                 \
  {                                                                                \
    const float* p_ = Xbase + (size_t)(S) * 32 * D1;                               \
    _Pragma("unroll")                                                              \
    for (int r_ = 0; r_ < 8; ++r_) xr[r_] = p_[(size_t)r_ * D1];                   \
    const int ib_ = ks0 * 32 + (S) * 32 + ak8;                                     \
    bv0 = *reinterpret_cast<const float4*>(bvec + ib_);                            \
    bv1 = *reinterpret_cast<const float4*>(bvec + ib_ + 4);                        \
    hv0 = *reinterpret_cast<const float4*>(h1v + ib_);                             \
    hv1 = *reinterpret_cast<const float4*>(h1v + ib_ + 4);                         \
  }

  GLL_B(0, 0);
  A_LOADS(0);

  for (int s = 0; s < nks; ++s) {
    const int buf = s & 1;
    {  // store A (pk-convert) + fused stats; compiler waits vmcnt for xr here
      union { uint32_t wd[4]; short8 v; } pk;
      pk.wd[0] = cvt_pk_bf16(xr[0], xr[1]);
      pk.wd[1] = cvt_pk_bf16(xr[2], xr[3]);
      pk.wd[2] = cvt_pk_bf16(xr[4], xr[5]);
      pk.wd[3] = cvt_pk_bf16(xr[6], xr[7]);
      const float bb[8] = {bv0.x, bv0.y, bv0.z, bv0.w, bv1.x, bv1.y, bv1.z, bv1.w};
      const float hh[8] = {hv0.x, hv0.y, hv0.z, hv0.w, hv1.x, hv1.y, hv1.z, hv1.w};
#pragma unroll
      for (int r = 0; r < 8; ++r) {
        const float x = xr[r];
        const float x2 = x * x;
        s1 += x2; sb += bb[r] * x2; sh += hh[r] * x2;
        sxa += x; cxa += bb[r] * x;
      }
      *reinterpret_cast<short8*>(&AB[buf][ab_st]) = pk.v;
    }
    __syncthreads();  // drains gll(s) + protects dbuf; the ONLY barrier per step
    if (s + 1 < nks) {  // prefetch: in flight across the whole next phase
      GLL_B(s + 1, buf ^ 1);
      A_LOADS(s + 1);
    }
    short8 af[4], bfv[4];
#pragma unroll
    for (int ps = 0; ps < 4; ++ps) {
      const int p = ps * 16 + lr;
      af[ps] = *reinterpret_cast<const short8*>(&AB[buf][p * 32 + ((lh ^ (p & 3)) << 3)]);
    }
#pragma unroll
    for (int q = 0; q < 4; ++q) {
      const int l = (w << 6) + (q << 4) + lr;
      bfv[q] = *reinterpret_cast<const short8*>(&NB[buf][l * 32 + ((lh ^ (l & 3)) << 3)]);
    }
#pragma unroll
    for (int ps = 0; ps < 4; ++ps)
#pragma unroll
      for (int q = 0; q < 4; ++q)
        acc[ps][q] = __builtin_amdgcn_mfma_f32_16x16x32_bf16(af[ps], bfv[q], acc[ps][q], 0, 0, 0);
  }
#undef GLL_B
#undef A_LOADS

  // M slice store [l][p] bf16; C/D layout col=lane&15 (l), row=(lane>>4)*4+e (p)
  uint16_t* Mk = Mb + (size_t)kc * ((size_t)D1 * 256);
#pragma unroll
  for (int ps = 0; ps < 4; ++ps)
#pragma unroll
    for (int q = 0; q < 4; ++q) {
      const int l = (w << 6) + (q << 4) + lr;
      const int p0e = pbase + ps * 16 + lh * 4;
      ushort4 st;
      st.x = f2bf(acc[ps][q][0]); st.y = f2bf(acc[ps][q][1]);
      st.z = f2bf(acc[ps][q][2]); st.w = f2bf(acc[ps][q][3]);
      *reinterpret_cast<ushort4*>(&Mk[(size_t)l * D1 + p0e]) = st;
    }

  // column stats
  atomicAdd(&sx[pbase + ap], sxa);
  atomicAdd(&cx[pbase + ap], cxa);

  // scalar stats: wave reduce -> one slotted atomic per wave (no LDS scratch)
  s1 = waveReduceSum(s1); sb = waveReduceSum(sb); sh = waveReduceSum(sh);
  if (lane == 0) {
    float* slotp = scalA + (size_t)(((blockIdx.x << 2) + w) & 63) * 4;
    atomicAdd(&slotp[0], s1);
    atomicAdd(&slotp[1], sb);
    atomicAdd(&slotp[2], sh);
  }
}

// ---------------- F = sum over elements of (sum_c m_c)^2, bf16 slices
__global__ __launch_bounds__(256) void k_square(const uint16_t* __restrict__ Mb,
                                                float* __restrict__ Fp,
                                                int n8, size_t slice, int nslice) {
  __shared__ float red[4];
  float s = 0.f;
  for (int idx = blockIdx.x * 256 + threadIdx.x; idx < n8; idx += gridDim.x * 256) {
    float v[8] = {0.f, 0.f, 0.f, 0.f, 0.f, 0.f, 0.f, 0.f};
    for (int c = 0; c < nslice; ++c) {
      union { short8 v8; uint16_t u[8]; } m;
      m.v8 = *reinterpret_cast<const short8*>(Mb + (size_t)idx * 8 + (size_t)c * slice);
#pragma unroll
      for (int e = 0; e < 8; ++e) v[e] += bf2f(m.u[e]);
    }
#pragma unroll
    for (int e = 0; e < 8; ++e) s += v[e] * v[e];
  }
  s = waveReduceSum(s);
  const int wave = threadIdx.x >> 6, lane = threadIdx.x & 63;
  if (lane == 0) red[wave] = s;
  __syncthreads();
  if (threadIdx.x == 0) atomicAdd(Fp, red[0] + red[1] + red[2] + red[3]);
}

// ---------------- final combine (slot-array scalars)
__global__ __launch_bounds__(256) void k_final4(const float* __restrict__ scalA,
                                                const float* __restrict__ Fp,
                                                const float* __restrict__ b,
                                                const float* __restrict__ sx,
                                                const float* __restrict__ cx,
                                                float* __restrict__ out,
                                                int B, int D1) {
  const int tid = threadIdx.x;
  float sa_ = 0.f, sab_ = 0.f, t1_ = 0.f, sb_ = 0.f, t2_ = 0.f;
  if (tid < 64) {
    sa_ = scalA[tid * 4 + 0];
    sab_ = scalA[tid * 4 + 1];
    t1_ = scalA[tid * 4 + 2];
  }
  for (int i = tid; i < B; i += 256) sb_ += b[i];
  for (int k = tid; k < D1; k += 256) t2_ += sx[k] * cx[k];
  sa_ = waveReduceSum(sa_); sab_ = waveReduceSum(sab_); t1_ = waveReduceSum(t1_);
  sb_ = waveReduceSum(sb_); t2_ = waveReduceSum(t2_);
  __shared__ float R[5][4];
  const int wave = tid >> 6, lane = tid & 63;
  if (lane == 0) { R[0][wave] = sa_; R[1][wave] = sab_; R[2][wave] = t1_; R[3][wave] = sb_; R[4][wave] = t2_; }
  __syncthreads();
  if (tid == 0) {
    double Sa = 0, Sab = 0, T1 = 0, Sb = 0, T2 = 0;
    for (int w = 0; w < 4; ++w) {
      Sa += R[0][w]; Sab += R[1][w]; T1 += R[2][w]; Sb += R[3][w]; T2 += R[4][w];
    }
    const double F = (double)Fp[0];
    const double total = 2.0 * (double)B * Sab + 2.0 * Sa * Sb - 4.0 * T1 - 4.0 * T2 + 4.0 * F;
    const double denom = (double)D1 * 256.0 * (double)B * (double)B;
    out[0] = (float)exp(-total / denom);
  }
}

// ================= tier-2 fallback (round-3 verified path) =================
__global__ __launch_bounds__(256, 3) void k_gemm_f3(const float* __restrict__ X,
                                                    const uint16_t* __restrict__ Nt,
                                                    uint16_t* __restrict__ Mb,
                                                    const float* __restrict__ bvec,
                                                    const float* __restrict__ h1v,
                                                    float* __restrict__ sx,
                                                    float* __restrict__ cx,
                                                    float* __restrict__ scal,
                                                    int B, int D1) {
  __shared__ __align__(16) uint16_t NB[2][8192];
  __shared__ __align__(16) uint16_t AB[2][64 * 40];
  __shared__ float SR[3][4];
  const int tid = threadIdx.x;
  const int w = tid >> 6, lane = tid & 63;
  const int lr = lane & 15, lh = lane >> 4;
  const int nks = B >> 7;
  const int pt = blockIdx.x >> 2, kc = blockIdx.x & 3;
  const int pbase = pt << 6;
  const int ks0 = kc * nks;

  f32x4 acc[4][4];
#pragma unroll
  for (int i = 0; i < 4; ++i)
#pragma unroll
    for (int j = 0; j < 4; ++j) acc[i][j] = (f32x4){0.f, 0.f, 0.f, 0.f};

  const int ap = tid & 63, ak8 = (tid >> 6) << 3;
  const float* Xbase = X + (size_t)(ks0 * 32 + ak8) * D1 + pbase + ap;
  float xr[8];
  float4 bv0, bv1, hv0, hv1;
  float s1 = 0.f, sb = 0.f, sh = 0.f, sxa = 0.f, cxa = 0.f;

#define GLL_B(S, BUF)                                                              \
  {                                                                                \
    const char* gsrc_ = (const char*)Nt + (size_t)(ks0 + (S)) * 16384 +            \
                        ((size_t)w << 10) + (size_t)lane * 16;                     \
    _Pragma("unroll")                                                              \
    for (int j_ = 0; j_ < 4; ++j_) {                                               \
      __builtin_amdgcn_global_load_lds((g_u32*)(gsrc_ + ((size_t)j_ << 12)),       \
                                       (l_u32*)&NB[BUF][(j_ * 4 + w) << 9],        \
                                       16, 0, 0);                                  \
    }                                                                              \
  }
#define A_LOADS(S)                                                                 \
  {                                                                                \
    const float* p_ = Xbase + (size_t)(S) * 32 * D1;                               \
    _Pragma("unroll")                                                              \
    for (int r_ = 0; r_ < 8; ++r_) xr[r_] = p_[(size_t)r_ * D1];                   \
    const int ib_ = ks0 * 32 + (S) * 32 + ak8;                                     \
    bv0 = *reinterpret_cast<const float4*>(bvec + ib_);                            \
    bv1 = *reinterpret_cast<const float4*>(bvec + ib_ + 4);                        \
    hv0 = *reinterpret_cast<const float4*>(h1v + ib_);                             \
    hv1 = *reinterpret_cast<const float4*>(h1v + ib_ + 4);                         \
  }

  GLL_B(0, 0);
  A_LOADS(0);

  for (int s = 0; s < nks; ++s) {
    const int buf = s & 1;
    {
      union { uint16_t u[8]; short8 v; } pk;
      const float bb[8] = {bv0.x, bv0.y, bv0.z, bv0.w, bv1.x, bv1.y, bv1.z, bv1.w};
      const float hh[8] = {hv0.x, hv0.y, hv0.z, hv0.w, hv1.x, hv1.y, hv1.z, hv1.w};
#pragma unroll
      for (int r = 0; r < 8; ++r) {
        const float x = xr[r];
        pk.u[r] = f2bf(x);
        const float x2 = x * x;
        s1 += x2; sb += bb[r] * x2; sh += hh[r] * x2;
        sxa += x; cxa += bb[r] * x;
      }
      *reinterpret_cast<short8*>(&AB[buf][ap * 40 + ak8]) = pk.v;
    }
    __syncthreads();
    if (s + 1 < nks) {
      GLL_B(s + 1, buf ^ 1);
      A_LOADS(s + 1);
    }
    short8 af[4], bfv[4];
#pragma unroll
    for (int ps = 0; ps < 4; ++ps)
      af[ps] = *reinterpret_cast<const short8*>(&AB[buf][(ps * 16 + lr) * 40 + lh * 8]);
#pragma unroll
    for (int q = 0; q < 4; ++q) {
      const int l = (w << 6) + (q << 4) + lr;
      bfv[q] = *reinterpret_cast<const short8*>(&NB[buf][l * 32 + ((lh ^ (l & 3)) << 3)]);
    }
#pragma unroll
    for (int ps = 0; ps < 4; ++ps)
#pragma unroll
      for (int q = 0; q < 4; ++q)
        acc[ps][q] = __builtin_amdgcn_mfma_f32_16x16x32_bf16(af[ps], bfv[q], acc[ps][q], 0, 0, 0);
    __syncthreads();
  }
#undef GLL_B
#undef A_LOADS

  uint16_t* Mk = Mb + (size_t)kc * ((size_t)D1 * 256);
#pragma unroll
  for (int ps = 0; ps < 4; ++ps)
#pragma unroll
    for (int q = 0; q < 4; ++q) {
      const int l = (w << 6) + (q << 4) + lr;
      const int p0 = pbase + ps * 16 + lh * 4;
      ushort4 st;
      st.x = f2bf(acc[ps][q][0]); st.y = f2bf(acc[ps][q][1]);
      st.z = f2bf(acc[ps][q][2]); st.w = f2bf(acc[ps][q][3]);
      *reinterpret_cast<ushort4*>(&Mk[(size_t)l * D1 + p0]) = st;
    }

  atomicAdd(&sx[pbase + ap], sxa);
  atomicAdd(&cx[pbase + ap], cxa);

  s1 = waveReduceSum(s1); sb = waveReduceSum(sb); sh = waveReduceSum(sh);
  if (lane == 0) { SR[0][w] = s1; SR[1][w] = sb; SR[2][w] = sh; }
  __syncthreads();
  if (tid == 0) {
    atomicAdd(&scal[0], SR[0][0] + SR[0][1] + SR[0][2] + SR[0][3]);
    atomicAdd(&scal[1], SR[1][0] + SR[1][1] + SR[1][2] + SR[1][3]);
    atomicAdd(&scal[2], SR[2][0] + SR[2][1] + SR[2][2] + SR[2][3]);
  }
}

__global__ __launch_bounds__(256) void k_final3(const float* __restrict__ scal,
                                                const float* __restrict__ b,
                                                const float* __restrict__ sx,
                                                const float* __restrict__ cx,
                                                float* __restrict__ out,
                                                int B, int D1) {
  const int tid = threadIdx.x;
  float sb_ = 0.f, t2_ = 0.f;
  for (int i = tid; i < B; i += 256) sb_ += b[i];
  for (int k = tid; k < D1; k += 256) t2_ += sx[k] * cx[k];
  sb_ = waveReduceSum(sb_); t2_ = waveReduceSum(t2_);
  __shared__ float R[2][4];
  const int wave = tid >> 6, lane = tid & 63;
  if (lane == 0) { R[0][wave] = sb_; R[1][wave] = t2_; }
  __syncthreads();
  if (tid == 0) {
    double Sb = 0, T2 = 0;
    for (int w = 0; w < 4; ++w) { Sb += R[0][w]; T2 += R[1][w]; }
    const double Sa = scal[0], Sab = scal[1], T1 = scal[2], F = scal[3];
    const double total = 2.0 * (double)B * Sab + 2.0 * Sa * Sb - 4.0 * T1 - 4.0 * T2 + 4.0 * F;
    const double denom = (double)D1 * 256.0 * (double)B * (double)B;
    out[0] = (float)exp(-total / denom);
  }
}

extern "C" void kernel_launch(void* const* d_in, const int* in_sizes, int n_in,
                              void* d_out, int out_size, void* d_ws, size_t ws_size,
                              hipStream_t stream) {
  const float* noises = (const float*)d_in[0];   // [B, 256]
  const float* images = (const float*)d_in[1];   // [B, D1]
  const int B = in_sizes[0] / 256;               // 4096
  const int D1 = in_sizes[1] / B;                // 12288
  float* outf = (float*)d_out;
  float* ws = (float*)d_ws;

  // ---- tier-1 layout (floats) ----
  float* sx    = ws;                        // D1   (atomic, zeroed)
  float* cx    = ws + D1;                   // D1   (atomic, zeroed)
  float* sn    = ws + 2 * D1;               // 256  (atomic, zeroed)
  float* scalA = ws + 2 * D1 + 256;         // 64*4 (atomic, zeroed)
  float* Fp    = ws + 2 * D1 + 512;         // 1    (atomic, zeroed; pad to 544)
  float* b     = ws + 2 * D1 + 544;         // B (fully written)
  float* h1    = b + B;                     // B (fully written)
  const size_t nt_off = ((size_t)2 * D1 + 544 + 2 * (size_t)B + 3) & ~(size_t)3;
  uint16_t* Nt = (uint16_t*)(ws + nt_off);                    // B*256 u16
  const size_t mb_off = nt_off + ((size_t)B * 256) / 2;
  uint16_t* Mb = (uint16_t*)(ws + mb_off);                    // 8*D1*256 u16
  const size_t need1 = (mb_off + 4 * (size_t)D1 * 256) * sizeof(float);

  if (ws_size >= need1) {
    const int nzero4 = (2 * D1 + 544) / 4;
    k_zero<<<(nzero4 + 255) / 256, 256, 0, stream>>>(ws, nzero4);
    k_nt<<<B / 64, 256, 0, stream>>>(noises, Nt, b, sn);
    k_h1<<<B / 4, 256, 0, stream>>>(noises, sn, h1);
    k_gemm_f5<<<(D1 / 64) * 8, 256, 0, stream>>>(images, Nt, Mb, b, h1, sx, cx, scalA, B, D1);
    k_square<<<512, 256, 0, stream>>>(Mb, Fp, D1 * 256 / 8, (size_t)D1 * 256, 8);
    k_final4<<<1, 256, 0, stream>>>(scalA, Fp, b, sx, cx, outf, B, D1);
  } else {
    // tier-2: round-3 verified path (ws >= ~28.3 MB established)
    float* sx2   = ws;
    float* cx2   = ws + D1;
    float* sn2   = ws + 2 * D1;
    float* scal2 = ws + 2 * D1 + 256;        // {Sa, Sab, T1, F}
    float* b2    = ws + 2 * D1 + 272;
    float* h12   = b2 + B;
    const size_t nt2_off = ((size_t)2 * D1 + 272 + 2 * (size_t)B + 3) & ~(size_t)3;
    uint16_t* Nt2 = (uint16_t*)(ws + nt2_off);
    const size_t mb2_off = nt2_off + ((size_t)B * 256) / 2;
    uint16_t* Mb2 = (uint16_t*)(ws + mb2_off);
    const int nzero4 = (2 * D1 + 272) / 4;
    k_zero<<<(nzero4 + 255) / 256, 256, 0, stream>>>(ws, nzero4);
    k_nt<<<B / 64, 256, 0, stream>>>(noises, Nt2, b2, sn2);
    k_h1<<<B / 4, 256, 0, stream>>>(noises, sn2, h12);
    k_gemm_f3<<<(D1 / 64) * 4, 256, 0, stream>>>(images, Nt2, Mb2, b2, h12, sx2, cx2, scal2, B, D1);
    k_square<<<512, 256, 0, stream>>>(Mb2, &scal2[3], D1 * 256 / 8, (size_t)D1 * 256, 4);
    k_final3<<<1, 256, 0, stream>>>(scal2, b2, sx2, cx2, outf, B, D1);
  }
}

// Round 6
// 156.479 us; speedup vs baseline: 2.6237x; 2.6237x over previous
//
#include <hip/hip_runtime.h>
#include <stdint.h>
#include <math.h>

typedef __attribute__((ext_vector_type(8))) short short8;   // 8 bf16 (4 VGPRs)
typedef __attribute__((ext_vector_type(4))) float f32x4;    // 4 fp32 acc

typedef __attribute__((address_space(1))) const uint32_t g_u32;
typedef __attribute__((address_space(3))) uint32_t l_u32;

static __device__ __forceinline__ uint16_t f2bf(float f) {
  union { float f; uint32_t u; } v; v.f = f;
  uint32_t r = (v.u + 0x7FFFu + ((v.u >> 16) & 1u)) >> 16;  // RNE
  return (uint16_t)r;
}

static __device__ __forceinline__ float bf2f(uint16_t u) {
  union { uint32_t u; float f; } v; v.u = ((uint32_t)u) << 16;
  return v.f;
}

static __device__ __forceinline__ uint32_t cvt_pk_bf16(float lo, float hi) {
  uint32_t r;
  asm("v_cvt_pk_bf16_f32 %0, %1, %2" : "=v"(r) : "v"(lo), "v"(hi));  // RNE pack
  return r;
}

static __device__ __forceinline__ float waveReduceSum(float x) {
#pragma unroll
  for (int m = 32; m > 0; m >>= 1) x += __shfl_xor(x, m, 64);
  return x;
}

// ---------------- zero the atomically-accumulated arrays (replaces memset)
__global__ __launch_bounds__(256) void k_zero(float* __restrict__ p, int n4) {
  const int i = blockIdx.x * 256 + threadIdx.x;
  if (i < n4) reinterpret_cast<float4*>(p)[i] = float4{0.f, 0.f, 0.f, 0.f};
}

// ---------------- N pass: b_i = ||n_i||^2, sn_l = sum_i N[i][l], Nt = bf16 N^T
// pre-swizzled per 32-k tile so a LINEAR 16KB gll copy yields swizzled LDS:
//   tile byte(l, k') = l*64 + ((k'>>3) ^ (l&3))*16 + (k'&7)*2,  k' in [0,32)
__global__ __launch_bounds__(256) void k_nt(const float* __restrict__ N,
                                            uint16_t* __restrict__ Nt,
                                            float* __restrict__ b,
                                            float* __restrict__ sn) {
  __shared__ __align__(16) uint16_t T[256 * 72];  // [l][k] k=0..63, pad 72
  const int i0 = blockIdx.x * 64;
  const int tid = threadIdx.x;
  const int wave = tid >> 6, lane = tid & 63;
  float sq[16];
  float snacc0 = 0.f, snacc1 = 0.f, snacc2 = 0.f, snacc3 = 0.f;
#pragma unroll
  for (int it = 0; it < 16; ++it) {
    const int k = wave + it * 4;
    const int l4 = lane * 4;
    const float4 v = *reinterpret_cast<const float4*>(N + (size_t)(i0 + k) * 256 + l4);
    T[(l4 + 0) * 72 + k] = f2bf(v.x);
    T[(l4 + 1) * 72 + k] = f2bf(v.y);
    T[(l4 + 2) * 72 + k] = f2bf(v.z);
    T[(l4 + 3) * 72 + k] = f2bf(v.w);
    sq[it] = v.x * v.x + v.y * v.y + v.z * v.z + v.w * v.w;
    snacc0 += v.x; snacc1 += v.y; snacc2 += v.z; snacc3 += v.w;
  }
#pragma unroll
  for (int m = 1; m < 64; m <<= 1) {
#pragma unroll
    for (int it = 0; it < 16; ++it) sq[it] += __shfl_xor(sq[it], m, 64);
  }
  float myv = sq[0];
#pragma unroll
  for (int it = 1; it < 16; ++it) myv = (lane == it) ? sq[it] : myv;
  if (lane < 16) b[i0 + wave + lane * 4] = myv;
  {
    const int l4 = lane * 4;
    atomicAdd(&sn[l4 + 0], snacc0); atomicAdd(&sn[l4 + 1], snacc1);
    atomicAdd(&sn[l4 + 2], snacc2); atomicAdd(&sn[l4 + 3], snacc3);
  }
  __syncthreads();
  const int l = tid;
#pragma unroll
  for (int tt = 0; tt < 2; ++tt) {
    const int tg = blockIdx.x * 2 + tt;
#pragma unroll
    for (int c = 0; c < 4; ++c) {
      const short8 v = *reinterpret_cast<const short8*>(&T[l * 72 + tt * 32 + c * 8]);
      *reinterpret_cast<short8*>((char*)Nt + (size_t)tg * 16384 + l * 64 +
                                 ((c ^ (l & 3)) << 4)) = v;
    }
  }
}

// ---------------- h1_i = sum_l N[i][l] * sn[l]
__global__ __launch_bounds__(256) void k_h1(const float* __restrict__ N,
                                            const float* __restrict__ sn,
                                            float* __restrict__ h1) {
  const int wave = threadIdx.x >> 6, lane = threadIdx.x & 63;
  const int i = blockIdx.x * 4 + wave;
  const float4 v = *reinterpret_cast<const float4*>(N + (size_t)i * 256 + lane * 4);
  const float4 s = *reinterpret_cast<const float4*>(sn + lane * 4);
  float d = v.x * s.x + v.y * s.y + v.z * s.z + v.w * s.w;
  d = waveReduceSum(d);
  if (lane == 0) h1[i] = d;
}

// ---------------- K-split-4 GEMM + fused X statistics (the ONLY full X read).
// r3 structure, but: ONE asm s_barrier per K-step with COUNTED s_waitcnt
// vmcnt(12) (T4), and distance-2 prefetch for the X register loads (xrA/xrB
// alternate). Issue order per step (fixed, the vmcnt count depends on it):
//   [step s-1]: gll(s) x4, bh(s) x4, x(s+1) x8
//   [step s]:   cvt/store(s) -> lgkm(0), vmcnt(12), barrier -> frag ds_reads
//               -> gll(s+1) x4 -> stats(s) -> bh(s+1) x4 -> x(s+2) x8 -> MFMA
// vmcnt(12) waits exactly for gll(s) (12 newer: bh(s)+x(s+1)). Tail steps
// keep the count uniform via clamped (harmless) prefetches.
__global__ __launch_bounds__(256) void k_gemm_f6(const float* __restrict__ X,
                                                 const uint16_t* __restrict__ Nt,
                                                 uint16_t* __restrict__ Mb,
                                                 const float* __restrict__ bvec,
                                                 const float* __restrict__ h1v,
                                                 float* __restrict__ sx,
                                                 float* __restrict__ cx,
                                                 float* __restrict__ scalA,
                                                 int B, int D1) {
  __shared__ __align__(16) uint16_t NB[2][8192];   // 2 x 16 KB (256l x 32k swz)
  __shared__ __align__(16) uint16_t AB[2][2048];   // 2 x 4 KB  (64p x 32k swz)
  const int tid = threadIdx.x;
  const int w = tid >> 6, lane = tid & 63;
  const int lr = lane & 15, lh = lane >> 4;
  const int nks = B >> 7;                 // 32 ksteps per chunk
  const int pt = blockIdx.x >> 2, kc = blockIdx.x & 3;
  const int pbase = pt << 6;
  const int ks0 = kc * nks;

  f32x4 acc[4][4];
#pragma unroll
  for (int i = 0; i < 4; ++i)
#pragma unroll
    for (int j = 0; j < 4; ++j) acc[i][j] = (f32x4){0.f, 0.f, 0.f, 0.f};

  // A staging: thread owns col p = tid&63, k-octet w (wave id) per 32-row step
  const int ap = tid & 63, ak8 = w << 3;
  const int ab_st = ap * 32 + ((w ^ (ap & 3)) << 3);  // swizzled u16 index
  const float* Xbase = X + (size_t)(ks0 * 32 + ak8) * D1 + pbase + ap;
  float xrA[8], xrB[8];
  float4 bv0, bv1, hv0, hv1;
  float s1 = 0.f, sb = 0.f, sh = 0.f, sxa = 0.f, cxa = 0.f;

#define GLL_B(S, BUF)                                                              \
  {                                                                                \
    const char* gsrc_ = (const char*)Nt + (size_t)(ks0 + (S)) * 16384 +            \
                        ((size_t)w << 10) + (size_t)lane * 16;                     \
    _Pragma("unroll")                                                              \
    for (int j_ = 0; j_ < 4; ++j_) {                                               \
      __builtin_amdgcn_global_load_lds((g_u32*)(gsrc_ + ((size_t)j_ << 12)),       \
                                       (l_u32*)&NB[BUF][(j_ * 4 + w) << 9],        \
                                       16, 0, 0);                                  \
    }                                                                              \
  }
#define X_LOADS(S, XR)                                                             \
  {                                                                                \
    const float* p_ = Xbase + (size_t)(S) * 32 * D1;                               \
    _Pragma("unroll")                                                              \
    for (int r_ = 0; r_ < 8; ++r_) XR[r_] = p_[(size_t)r_ * D1];                   \
  }
#define BH_LOADS(S)                                                                \
  {                                                                                \
    const int ib_ = (ks0 + (S)) * 32 + ak8;                                        \
    bv0 = *reinterpret_cast<const float4*>(bvec + ib_);                            \
    bv1 = *reinterpret_cast<const float4*>(bvec + ib_ + 4);                        \
    hv0 = *reinterpret_cast<const float4*>(h1v + ib_);                             \
    hv1 = *reinterpret_cast<const float4*>(h1v + ib_ + 4);                         \
  }

#define STEP(S, BUF, XR)                                                           \
  {                                                                                \
    {  /* 1. cvt + LDS store of A(s); auto counted-wait for XR */                  \
      union { uint32_t wd[4]; short8 v; } pk;                                      \
      pk.wd[0] = cvt_pk_bf16(XR[0], XR[1]);                                        \
      pk.wd[1] = cvt_pk_bf16(XR[2], XR[3]);                                        \
      pk.wd[2] = cvt_pk_bf16(XR[4], XR[5]);                                        \
      pk.wd[3] = cvt_pk_bf16(XR[6], XR[7]);                                        \
      *reinterpret_cast<short8*>(&AB[BUF][ab_st]) = pk.v;                          \
    }                                                                              \
    /* 2. counted waits + barrier: gll(S) done, 12 newer prefetches survive */     \
    asm volatile("s_waitcnt lgkmcnt(0)" ::: "memory");                             \
    asm volatile("s_waitcnt vmcnt(12)" ::: "memory");                              \
    __builtin_amdgcn_s_barrier();                                                  \
    __builtin_amdgcn_sched_barrier(0);                                             \
    /* 3. frag ds_reads (before next gll: keeps compiler waits counted) */         \
    short8 af[4], bfv[4];                                                          \
    _Pragma("unroll")                                                              \
    for (int ps = 0; ps < 4; ++ps) {                                               \
      const int p_ = ps * 16 + lr;                                                 \
      af[ps] = *reinterpret_cast<const short8*>(                                   \
          &AB[BUF][p_ * 32 + ((lh ^ (p_ & 3)) << 3)]);                             \
    }                                                                              \
    _Pragma("unroll")                                                              \
    for (int q = 0; q < 4; ++q) {                                                  \
      const int l_ = (w << 6) + (q << 4) + lr;                                     \
      bfv[q] = *reinterpret_cast<const short8*>(                                   \
          &NB[BUF][l_ * 32 + ((lh ^ (l_ & 3)) << 3)]);                             \
    }                                                                              \
    /* 4. prefetches (clamped at tail -> uniform vmcnt count) */                   \
    const int sn1_ = ((S) + 1 < nks) ? (S) + 1 : nks - 1;                          \
    const int sn2_ = ((S) + 2 < nks) ? (S) + 2 : nks - 1;                          \
    GLL_B(sn1_, (BUF) ^ 1);                                                        \
    {  /* 5. stats from fp32 XR + current bv/hv */                                 \
      const float bb[8] = {bv0.x, bv0.y, bv0.z, bv0.w, bv1.x, bv1.y, bv1.z, bv1.w};\
      const float hh[8] = {hv0.x, hv0.y, hv0.z, hv0.w, hv1.x, hv1.y, hv1.z, hv1.w};\
      _Pragma("unroll")                                                            \
      for (int r = 0; r < 8; ++r) {                                                \
        const float x_ = XR[r];                                                    \
        const float x2_ = x_ * x_;                                                 \
        s1 += x2_; sb += bb[r] * x2_; sh += hh[r] * x2_;                           \
        sxa += x_; cxa += bb[r] * x_;                                              \
      }                                                                            \
    }                                                                              \
    BH_LOADS(sn1_);                                                                \
    X_LOADS(sn2_, XR);                                                             \
    /* 6. MFMA (compiler inserts lgkm waits for the frag reads) */                 \
    _Pragma("unroll")                                                              \
    for (int ps = 0; ps < 4; ++ps)                                                 \
      _Pragma("unroll")                                                            \
      for (int q = 0; q < 4; ++q)                                                  \
        acc[ps][q] =                                                               \
            __builtin_amdgcn_mfma_f32_16x16x32_bf16(af[ps], bfv[q], acc[ps][q],    \
                                                    0, 0, 0);                      \
  }

  // prologue: gll(0) first, then x(0), bh(0), x(1) -> cvt's auto-wait drains gll(0)
  GLL_B(0, 0);
  X_LOADS(0, xrA);
  BH_LOADS(0);
  X_LOADS(1, xrB);

  for (int s = 0; s < nks; s += 2) {
    STEP(s, 0, xrA);
    STEP(s + 1, 1, xrB);
  }
#undef GLL_B
#undef X_LOADS
#undef BH_LOADS
#undef STEP

  // M slice store [l][p] bf16; C/D layout col=lane&15 (l), row=(lane>>4)*4+e (p)
  uint16_t* Mk = Mb + (size_t)kc * ((size_t)D1 * 256);
#pragma unroll
  for (int ps = 0; ps < 4; ++ps)
#pragma unroll
    for (int q = 0; q < 4; ++q) {
      const int l = (w << 6) + (q << 4) + lr;
      const int p0e = pbase + ps * 16 + lh * 4;
      ushort4 st;
      st.x = f2bf(acc[ps][q][0]); st.y = f2bf(acc[ps][q][1]);
      st.z = f2bf(acc[ps][q][2]); st.w = f2bf(acc[ps][q][3]);
      *reinterpret_cast<ushort4*>(&Mk[(size_t)l * D1 + p0e]) = st;
    }

  // column stats
  atomicAdd(&sx[pbase + ap], sxa);
  atomicAdd(&cx[pbase + ap], cxa);

  // scalar stats: wave reduce -> one slotted atomic per wave
  s1 = waveReduceSum(s1); sb = waveReduceSum(sb); sh = waveReduceSum(sh);
  if (lane == 0) {
    float* slotp = scalA + (size_t)(((blockIdx.x << 2) + w) & 63) * 4;
    atomicAdd(&slotp[0], s1);
    atomicAdd(&slotp[1], sb);
    atomicAdd(&slotp[2], sh);
  }
}

// ---------------- F = sum over elements of (sum_c m_c)^2, bf16 slices
__global__ __launch_bounds__(256) void k_square(const uint16_t* __restrict__ Mb,
                                                float* __restrict__ Fp,
                                                int n8, size_t slice, int nslice) {
  __shared__ float red[4];
  float s = 0.f;
  for (int idx = blockIdx.x * 256 + threadIdx.x; idx < n8; idx += gridDim.x * 256) {
    float v[8] = {0.f, 0.f, 0.f, 0.f, 0.f, 0.f, 0.f, 0.f};
    for (int c = 0; c < nslice; ++c) {
      union { short8 v8; uint16_t u[8]; } m;
      m.v8 = *reinterpret_cast<const short8*>(Mb + (size_t)idx * 8 + (size_t)c * slice);
#pragma unroll
      for (int e = 0; e < 8; ++e) v[e] += bf2f(m.u[e]);
    }
#pragma unroll
    for (int e = 0; e < 8; ++e) s += v[e] * v[e];
  }
  s = waveReduceSum(s);
  const int wave = threadIdx.x >> 6, lane = threadIdx.x & 63;
  if (lane == 0) red[wave] = s;
  __syncthreads();
  if (threadIdx.x == 0) atomicAdd(Fp, red[0] + red[1] + red[2] + red[3]);
}

// ---------------- final combine (slot-array scalars)
__global__ __launch_bounds__(256) void k_final4(const float* __restrict__ scalA,
                                                const float* __restrict__ Fp,
                                                const float* __restrict__ b,
                                                const float* __restrict__ sx,
                                                const float* __restrict__ cx,
                                                float* __restrict__ out,
                                                int B, int D1) {
  const int tid = threadIdx.x;
  float sa_ = 0.f, sab_ = 0.f, t1_ = 0.f, sb_ = 0.f, t2_ = 0.f;
  if (tid < 64) {
    sa_ = scalA[tid * 4 + 0];
    sab_ = scalA[tid * 4 + 1];
    t1_ = scalA[tid * 4 + 2];
  }
  for (int i = tid; i < B; i += 256) sb_ += b[i];
  for (int k = tid; k < D1; k += 256) t2_ += sx[k] * cx[k];
  sa_ = waveReduceSum(sa_); sab_ = waveReduceSum(sab_); t1_ = waveReduceSum(t1_);
  sb_ = waveReduceSum(sb_); t2_ = waveReduceSum(t2_);
  __shared__ float R[5][4];
  const int wave = tid >> 6, lane = tid & 63;
  if (lane == 0) { R[0][wave] = sa_; R[1][wave] = sab_; R[2][wave] = t1_; R[3][wave] = sb_; R[4][wave] = t2_; }
  __syncthreads();
  if (tid == 0) {
    double Sa = 0, Sab = 0, T1 = 0, Sb = 0, T2 = 0;
    for (int w = 0; w < 4; ++w) {
      Sa += R[0][w]; Sab += R[1][w]; T1 += R[2][w]; Sb += R[3][w]; T2 += R[4][w];
    }
    const double F = (double)Fp[0];
    const double total = 2.0 * (double)B * Sab + 2.0 * Sa * Sb - 4.0 * T1 - 4.0 * T2 + 4.0 * F;
    const double denom = (double)D1 * 256.0 * (double)B * (double)B;
    out[0] = (float)exp(-total / denom);
  }
}

// ================= tier-2 fallback (round-3 verified path) =================
__global__ __launch_bounds__(256, 3) void k_gemm_f3(const float* __restrict__ X,
                                                    const uint16_t* __restrict__ Nt,
                                                    uint16_t* __restrict__ Mb,
                                                    const float* __restrict__ bvec,
                                                    const float* __restrict__ h1v,
                                                    float* __restrict__ sx,
                                                    float* __restrict__ cx,
                                                    float* __restrict__ scal,
                                                    int B, int D1) {
  __shared__ __align__(16) uint16_t NB[2][8192];
  __shared__ __align__(16) uint16_t AB[2][64 * 40];
  __shared__ float SR[3][4];
  const int tid = threadIdx.x;
  const int w = tid >> 6, lane = tid & 63;
  const int lr = lane & 15, lh = lane >> 4;
  const int nks = B >> 7;
  const int pt = blockIdx.x >> 2, kc = blockIdx.x & 3;
  const int pbase = pt << 6;
  const int ks0 = kc * nks;

  f32x4 acc[4][4];
#pragma unroll
  for (int i = 0; i < 4; ++i)
#pragma unroll
    for (int j = 0; j < 4; ++j) acc[i][j] = (f32x4){0.f, 0.f, 0.f, 0.f};

  const int ap = tid & 63, ak8 = (tid >> 6) << 3;
  const float* Xbase = X + (size_t)(ks0 * 32 + ak8) * D1 + pbase + ap;
  float xr[8];
  float4 bv0, bv1, hv0, hv1;
  float s1 = 0.f, sb = 0.f, sh = 0.f, sxa = 0.f, cxa = 0.f;

#define GLL_B(S, BUF)                                                              \
  {                                                                                \
    const char* gsrc_ = (const char*)Nt + (size_t)(ks0 + (S)) * 16384 +            \
                        ((size_t)w << 10) + (size_t)lane * 16;                     \
    _Pragma("unroll")                                                              \
    for (int j_ = 0; j_ < 4; ++j_) {                                               \
      __builtin_amdgcn_global_load_lds((g_u32*)(gsrc_ + ((size_t)j_ << 12)),       \
                                       (l_u32*)&NB[BUF][(j_ * 4 + w) << 9],        \
                                       16, 0, 0);                                  \
    }                                                                              \
  }
#define A_LOADS(S)                                                                 \
  {                                                                                \
    const float* p_ = Xbase + (size_t)(S) * 32 * D1;                               \
    _Pragma("unroll")                                                              \
    for (int r_ = 0; r_ < 8; ++r_) xr[r_] = p_[(size_t)r_ * D1];                   \
    const int ib_ = ks0 * 32 + (S) * 32 + ak8;                                     \
    bv0 = *reinterpret_cast<const float4*>(bvec + ib_);                            \
    bv1 = *reinterpret_cast<const float4*>(bvec + ib_ + 4);                        \
    hv0 = *reinterpret_cast<const float4*>(h1v + ib_);                             \
    hv1 = *reinterpret_cast<const float4*>(h1v + ib_ + 4);                         \
  }

  GLL_B(0, 0);
  A_LOADS(0);

  for (int s = 0; s < nks; ++s) {
    const int buf = s & 1;
    {
      union { uint16_t u[8]; short8 v; } pk;
      const float bb[8] = {bv0.x, bv0.y, bv0.z, bv0.w, bv1.x, bv1.y, bv1.z, bv1.w};
      const float hh[8] = {hv0.x, hv0.y, hv0.z, hv0.w, hv1.x, hv1.y, hv1.z, hv1.w};
#pragma unroll
      for (int r = 0; r < 8; ++r) {
        const float x = xr[r];
        pk.u[r] = f2bf(x);
        const float x2 = x * x;
        s1 += x2; sb += bb[r] * x2; sh += hh[r] * x2;
        sxa += x; cxa += bb[r] * x;
      }
      *reinterpret_cast<short8*>(&AB[buf][ap * 40 + ak8]) = pk.v;
    }
    __syncthreads();
    if (s + 1 < nks) {
      GLL_B(s + 1, buf ^ 1);
      A_LOADS(s + 1);
    }
    short8 af[4], bfv[4];
#pragma unroll
    for (int ps = 0; ps < 4; ++ps)
      af[ps] = *reinterpret_cast<const short8*>(&AB[buf][(ps * 16 + lr) * 40 + lh * 8]);
#pragma unroll
    for (int q = 0; q < 4; ++q) {
      const int l = (w << 6) + (q << 4) + lr;
      bfv[q] = *reinterpret_cast<const short8*>(&NB[buf][l * 32 + ((lh ^ (l & 3)) << 3)]);
    }
#pragma unroll
    for (int ps = 0; ps < 4; ++ps)
#pragma unroll
      for (int q = 0; q < 4; ++q)
        acc[ps][q] = __builtin_amdgcn_mfma_f32_16x16x32_bf16(af[ps], bfv[q], acc[ps][q], 0, 0, 0);
    __syncthreads();
  }
#undef GLL_B
#undef A_LOADS

  uint16_t* Mk = Mb + (size_t)kc * ((size_t)D1 * 256);
#pragma unroll
  for (int ps = 0; ps < 4; ++ps)
#pragma unroll
    for (int q = 0; q < 4; ++q) {
      const int l = (w << 6) + (q << 4) + lr;
      const int p0 = pbase + ps * 16 + lh * 4;
      ushort4 st;
      st.x = f2bf(acc[ps][q][0]); st.y = f2bf(acc[ps][q][1]);
      st.z = f2bf(acc[ps][q][2]); st.w = f2bf(acc[ps][q][3]);
      *reinterpret_cast<ushort4*>(&Mk[(size_t)l * D1 + p0]) = st;
    }

  atomicAdd(&sx[pbase + ap], sxa);
  atomicAdd(&cx[pbase + ap], cxa);

  s1 = waveReduceSum(s1); sb = waveReduceSum(sb); sh = waveReduceSum(sh);
  if (lane == 0) { SR[0][w] = s1; SR[1][w] = sb; SR[2][w] = sh; }
  __syncthreads();
  if (tid == 0) {
    atomicAdd(&scal[0], SR[0][0] + SR[0][1] + SR[0][2] + SR[0][3]);
    atomicAdd(&scal[1], SR[1][0] + SR[1][1] + SR[1][2] + SR[1][3]);
    atomicAdd(&scal[2], SR[2][0] + SR[2][1] + SR[2][2] + SR[2][3]);
  }
}

__global__ __launch_bounds__(256) void k_final3(const float* __restrict__ scal,
                                                const float* __restrict__ b,
                                                const float* __restrict__ sx,
                                                const float* __restrict__ cx,
                                                float* __restrict__ out,
                                                int B, int D1) {
  const int tid = threadIdx.x;
  float sb_ = 0.f, t2_ = 0.f;
  for (int i = tid; i < B; i += 256) sb_ += b[i];
  for (int k = tid; k < D1; k += 256) t2_ += sx[k] * cx[k];
  sb_ = waveReduceSum(sb_); t2_ = waveReduceSum(t2_);
  __shared__ float R[2][4];
  const int wave = tid >> 6, lane = tid & 63;
  if (lane == 0) { R[0][wave] = sb_; R[1][wave] = t2_; }
  __syncthreads();
  if (tid == 0) {
    double Sb = 0, T2 = 0;
    for (int w = 0; w < 4; ++w) { Sb += R[0][w]; T2 += R[1][w]; }
    const double Sa = scal[0], Sab = scal[1], T1 = scal[2], F = scal[3];
    const double total = 2.0 * (double)B * Sab + 2.0 * Sa * Sb - 4.0 * T1 - 4.0 * T2 + 4.0 * F;
    const double denom = (double)D1 * 256.0 * (double)B * (double)B;
    out[0] = (float)exp(-total / denom);
  }
}

extern "C" void kernel_launch(void* const* d_in, const int* in_sizes, int n_in,
                              void* d_out, int out_size, void* d_ws, size_t ws_size,
                              hipStream_t stream) {
  const float* noises = (const float*)d_in[0];   // [B, 256]
  const float* images = (const float*)d_in[1];   // [B, D1]
  const int B = in_sizes[0] / 256;               // 4096
  const int D1 = in_sizes[1] / B;                // 12288
  float* outf = (float*)d_out;
  float* ws = (float*)d_ws;

  // ---- tier-1 layout (floats) ----
  float* sx    = ws;                        // D1   (atomic, zeroed)
  float* cx    = ws + D1;                   // D1   (atomic, zeroed)
  float* sn    = ws + 2 * D1;               // 256  (atomic, zeroed)
  float* scalA = ws + 2 * D1 + 256;         // 64*4 (atomic, zeroed)
  float* Fp    = ws + 2 * D1 + 512;         // 1    (atomic, zeroed; pad to 544)
  float* b     = ws + 2 * D1 + 544;         // B (fully written)
  float* h1    = b + B;                     // B (fully written)
  const size_t nt_off = ((size_t)2 * D1 + 544 + 2 * (size_t)B + 3) & ~(size_t)3;
  uint16_t* Nt = (uint16_t*)(ws + nt_off);                    // B*256 u16
  const size_t mb_off = nt_off + ((size_t)B * 256) / 2;
  uint16_t* Mb = (uint16_t*)(ws + mb_off);                    // 4*D1*256 u16
  const size_t need1 = (mb_off + 2 * (size_t)D1 * 256) * sizeof(float);

  if (ws_size >= need1 && (B & 255) == 0) {
    const int nzero4 = (2 * D1 + 544) / 4;
    k_zero<<<(nzero4 + 255) / 256, 256, 0, stream>>>(ws, nzero4);
    k_nt<<<B / 64, 256, 0, stream>>>(noises, Nt, b, sn);
    k_h1<<<B / 4, 256, 0, stream>>>(noises, sn, h1);
    k_gemm_f6<<<(D1 / 64) * 4, 256, 0, stream>>>(images, Nt, Mb, b, h1, sx, cx, scalA, B, D1);
    k_square<<<512, 256, 0, stream>>>(Mb, Fp, D1 * 256 / 8, (size_t)D1 * 256, 4);
    k_final4<<<1, 256, 0, stream>>>(scalA, Fp, b, sx, cx, outf, B, D1);
  } else {
    // tier-2: round-3 verified path
    float* sx2   = ws;
    float* cx2   = ws + D1;
    float* sn2   = ws + 2 * D1;
    float* scal2 = ws + 2 * D1 + 256;        // {Sa, Sab, T1, F}
    float* b2    = ws + 2 * D1 + 272;
    float* h12   = b2 + B;
    const size_t nt2_off = ((size_t)2 * D1 + 272 + 2 * (size_t)B + 3) & ~(size_t)3;
    uint16_t* Nt2 = (uint16_t*)(ws + nt2_off);
    const size_t mb2_off = nt2_off + ((size_t)B * 256) / 2;
    uint16_t* Mb2 = (uint16_t*)(ws + mb2_off);
    const int nzero4 = (2 * D1 + 272) / 4;
    k_zero<<<(nzero4 + 255) / 256, 256, 0, stream>>>(ws, nzero4);
    k_nt<<<B / 64, 256, 0, stream>>>(noises, Nt2, b2, sn2);
    k_h1<<<B / 4, 256, 0, stream>>>(noises, sn2, h12);
    k_gemm_f3<<<(D1 / 64) * 4, 256, 0, stream>>>(images, Nt2, Mb2, b2, h12, sx2, cx2, scal2, B, D1);
    k_square<<<512, 256, 0, stream>>>(Mb2, &scal2[3], D1 * 256 / 8, (size_t)D1 * 256, 4);
    k_final3<<<1, 256, 0, stream>>>(scal2, b2, sx2, cx2, outf, B, D1);
  }
}